// Round 1
// baseline (589.704 us; speedup 1.0000x reference)
//
#include <hip/hip_runtime.h>
#include <stdint.h>

// DropBlock: x(64,256,56,56) f32, u(64,256,52,52) f32, gamma scalar f32.
// mask = u < gamma; dilated = maxpool5x5(stride1, pad4)(mask) -> 56x56
// out = (1-dilated) * x * (countM / (count_ones + 1e-12))

#define BS      5
#define HH      56
#define WW      56
#define UH      52
#define UW      52
#define PLANES  (64 * 256)        // 16384
#define UPLANE  (UH * UW)         // 2704
#define XPLANE  (HH * WW)         // 3136
#define NWORDS  43                // ceil(2704 / 64)

// Kernel 1: per-plane seed mask -> 5x5 dilation (separable, bit-parallel),
// popcount -> global counter; dilated row-words stashed in out's plane region.
__global__ __launch_bounds__(256) void dropblock_dilate(
    const float* __restrict__ u, const float* __restrict__ gamma_p,
    float* __restrict__ out, unsigned int* __restrict__ counter)
{
    __shared__ unsigned long long lin[NWORDS];   // linear bit-packed seed mask
    __shared__ unsigned long long hrow[UH];      // horizontally dilated rows
    __shared__ unsigned int s_cnt;

    const int plane = blockIdx.x;
    const int tid   = threadIdx.x;
    if (tid == 0) s_cnt = 0;

    const float g = *gamma_p;
    const float* up = u + (size_t)plane * UPLANE;

    // Coalesced predicate load; ballot packs 64 consecutive bits per wave.
    for (int base = 0; base < UPLANE; base += 256) {
        int idx = base + tid;
        bool p = false;
        if (idx < UPLANE) p = (up[idx] < g);
        unsigned long long b = __ballot(p);
        if ((tid & 63) == 0) {
            int w = (base >> 6) + (tid >> 6);
            if (w < NWORDS) lin[w] = b;
        }
    }
    __syncthreads();

    // Extract 52-bit row r (bits [52r, 52r+52)), horizontal dilation -> 56 bits.
    if (tid < UH) {
        int bitpos = tid * UW;
        int a = bitpos >> 6, s = bitpos & 63;
        unsigned long long row = lin[a] >> s;
        if (s) row |= lin[a + 1] << (64 - s);
        row &= (1ULL << UW) - 1;
        hrow[tid] = row | (row << 1) | (row << 2) | (row << 3) | (row << 4);
    }
    __syncthreads();

    // Vertical dilation: output row h = OR of hrow[p], p in [h-4, h] ∩ [0,51].
    if (tid < HH) {
        int lo = tid - (BS - 1); if (lo < 0) lo = 0;
        int hi = tid;            if (hi > UH - 1) hi = UH - 1;
        unsigned long long d = 0;
        for (int p = lo; p <= hi; ++p) d |= hrow[p];
        // Stash the 56 row-words in this plane's own slice of out (448 B of
        // 12544 B). Kernel 2 reads them into LDS before overwriting the plane.
        unsigned long long* owd =
            reinterpret_cast<unsigned long long*>(out + (size_t)plane * XPLANE);
        owd[tid] = d;
        atomicAdd(&s_cnt, (unsigned int)__popcll(d));
    }
    __syncthreads();
    if (tid == 0) atomicAdd(counter, s_cnt);
}

// Kernel 2: per-plane, load mask words + counter, stream x -> out (float4).
__global__ __launch_bounds__(256) void dropblock_apply(
    const float* __restrict__ x, float* __restrict__ out,
    const unsigned int* __restrict__ counter)
{
    __shared__ unsigned long long wd[HH];
    __shared__ float s_scale;

    const int plane = blockIdx.x;
    const int tid   = threadIdx.x;

    const unsigned long long* owd =
        reinterpret_cast<const unsigned long long*>(out + (size_t)plane * XPLANE);
    if (tid < HH) wd[tid] = owd[tid];
    if (tid == 0) {
        const double countM = (double)((unsigned long long)PLANES * XPLANE);
        unsigned int dil = *counter;
        double count_ones = countM - (double)dil;
        s_scale = (float)(countM / (count_ones + 1e-12));
    }
    __syncthreads();

    const float scale = s_scale;
    const float4* xp = reinterpret_cast<const float4*>(x + (size_t)plane * XPLANE);
    float4*       op = reinterpret_cast<float4*>(out + (size_t)plane * XPLANE);

    for (int i4 = tid; i4 < XPLANE / 4; i4 += 256) {  // 784 float4 per plane
        int h     = i4 / 14;        // 14 float4 per row (56/4)
        int wbase = (i4 % 14) * 4;
        unsigned long long w = wd[h];
        float4 v = xp[i4];
        float4 r;
        r.x = ((w >> (wbase + 0)) & 1ULL) ? 0.f : v.x * scale;
        r.y = ((w >> (wbase + 1)) & 1ULL) ? 0.f : v.y * scale;
        r.z = ((w >> (wbase + 2)) & 1ULL) ? 0.f : v.z * scale;
        r.w = ((w >> (wbase + 3)) & 1ULL) ? 0.f : v.w * scale;
        op[i4] = r;
    }
}

extern "C" void kernel_launch(void* const* d_in, const int* in_sizes, int n_in,
                              void* d_out, int out_size, void* d_ws, size_t ws_size,
                              hipStream_t stream) {
    const float* x     = (const float*)d_in[0];
    const float* u     = (const float*)d_in[1];
    const float* gamma = (const float*)d_in[2];
    float* out = (float*)d_out;
    unsigned int* counter = (unsigned int*)d_ws;

    hipMemsetAsync(d_ws, 0, sizeof(unsigned int), stream);
    dropblock_dilate<<<PLANES, 256, 0, stream>>>(u, gamma, out, counter);
    dropblock_apply <<<PLANES, 256, 0, stream>>>(x, out, counter);
}